// Round 11
// baseline (74.496 us; speedup 1.0000x reference)
//
#include <hip/hip_runtime.h>

// <Z_q> = prod_{j<=q} cos(alpha_j)*cos(beta_j);  (alpha_j,beta_j) = rows 3j,3j+1 of x@W^T+b.
// CNOT chain -> Z-string observable on a product state; RZ cancels.
//
// R=4 rows per 64-lane wave: one LDS W-fragment read feeds 4 batch rows
// (12 ds_read_b128 per row -> LDS pipe ~2.0us < HBM floor 2.7us).
// k-split: lane l covers k4 = c*64+l, c=0..1 (512 f32 per row).
// Reduction: static-index reduce-scatter butterfly, masks 32,16 (row select)
// then 8,4,2,1 (dot scatter): lane ends with dot sums {2j, 2j+1}, j=l&15,
// for row (l>>4)&3. No runtime-indexed register arrays (no scratch).

#define NQ    12
#define NDOT  24
#define KDIM  512
#define ROWS_PER_BLOCK 16   // 4 waves * 4 rows

__global__ __launch_bounds__(256, 2) void qgate_kernel(
    const float* __restrict__ x,   // (8192, 512)
    const float* __restrict__ W,   // (36, 512)
    const float* __restrict__ b,   // (36,)
    float* __restrict__ out)       // (8192, 12)
{
    __shared__ float4 wlds[NDOT * 128];   // 24 rows (3j,3j+1) of W, 48 KB

    const int tid = threadIdx.x;
    for (int i = tid; i < NDOT * 128; i += 256) {
        const int d  = i >> 7;                  // 0..23
        const int kk = i & 127;                 // float4 within row
        const int r  = (d >> 1) * 3 + (d & 1);  // source row of W
        wlds[i] = reinterpret_cast<const float4*>(W)[r * 128 + kk];
    }
    __syncthreads();

    const int l    = tid & 63;                    // lane in wave
    const int w    = tid >> 6;                    // wave 0..3
    const int row0 = blockIdx.x * ROWS_PER_BLOCK + w * 4;

    // x fragments: 4 rows x 2 float4 per lane (coalesced 1KB/instr)
    float4 xv[4][2];
#pragma unroll
    for (int r = 0; r < 4; ++r) {
        const float4* __restrict__ xp =
            reinterpret_cast<const float4*>(x + (size_t)(row0 + r) * KDIM);
#pragma unroll
        for (int c = 0; c < 2; ++c) xv[r][c] = xp[c * 64 + l];
    }

    float acc[4][NDOT];
#pragma unroll
    for (int r = 0; r < 4; ++r)
#pragma unroll
        for (int d = 0; d < NDOT; ++d) acc[r][d] = 0.f;

#pragma unroll
    for (int c = 0; c < 2; ++c) {
#pragma unroll
        for (int d = 0; d < NDOT; ++d) {
            const float4 wv = wlds[d * 128 + c * 64 + l];   // one read, four rows
#pragma unroll
            for (int r = 0; r < 4; ++r) {
                acc[r][d] = fmaf(xv[r][c].x, wv.x, acc[r][d]);
                acc[r][d] = fmaf(xv[r][c].y, wv.y, acc[r][d]);
                acc[r][d] = fmaf(xv[r][c].z, wv.z, acc[r][d]);
                acc[r][d] = fmaf(xv[r][c].w, wv.w, acc[r][d]);
            }
        }
    }

    // --- mask-32: keep row pair {0,1} (lanes 0-31) or {2,3} (lanes 32-63) ---
    const bool h32 = (l & 32) != 0;
    float vA[2][NDOT];
#pragma unroll
    for (int r = 0; r < 2; ++r)
#pragma unroll
        for (int d = 0; d < NDOT; ++d) {
            const float keep = h32 ? acc[2 + r][d] : acc[r][d];
            const float send = h32 ? acc[r][d]     : acc[2 + r][d];
            vA[r][d] = keep + __shfl_xor(send, 32);
        }

    // --- mask-16: keep one row; lane's row = (l>>4)&3 ---
    const bool h16 = (l & 16) != 0;
    float v32[32];
#pragma unroll
    for (int d = 0; d < NDOT; ++d) {
        const float keep = h16 ? vA[1][d] : vA[0][d];
        const float send = h16 ? vA[0][d] : vA[1][d];
        v32[d] = keep + __shfl_xor(send, 16);
    }
#pragma unroll
    for (int d = NDOT; d < 32; ++d) v32[d] = 0.f;   // pad dots 24..31

    // --- dot scatter: masks 8,4,2,1 (static indices only) ---
    float u16[16];
#pragma unroll
    for (int i = 0; i < 16; ++i) {
        const float keep = (l & 8) ? v32[16 + i] : v32[i];
        const float send = (l & 8) ? v32[i] : v32[16 + i];
        u16[i] = keep + __shfl_xor(send, 8);
    }
    float u8[8];
#pragma unroll
    for (int i = 0; i < 8; ++i) {
        const float keep = (l & 4) ? u16[8 + i] : u16[i];
        const float send = (l & 4) ? u16[i] : u16[8 + i];
        u8[i] = keep + __shfl_xor(send, 4);
    }
    float u4[4];
#pragma unroll
    for (int i = 0; i < 4; ++i) {
        const float keep = (l & 2) ? u8[4 + i] : u8[i];
        const float send = (l & 2) ? u8[i] : u8[4 + i];
        u4[i] = keep + __shfl_xor(send, 2);
    }
    float u2[2];
#pragma unroll
    for (int i = 0; i < 2; ++i) {
        const float keep = (l & 1) ? u4[2 + i] : u4[i];
        const float send = (l & 1) ? u4[i] : u4[2 + i];
        u2[i] = keep + __shfl_xor(send, 1);
    }
    // lane now holds dot sums {2j, 2j+1}, j = l&15, for row (l>>4)&3

    const int j  = l & 15;
    const int jc = (j < NQ) ? j : NQ - 1;       // clamp: keep b[] reads in bounds
    const float aj = u2[0] + b[3 * jc];
    const float bj = u2[1] + b[3 * jc + 1];
    float p = __cosf(aj) * __cosf(bj);

#pragma unroll
    for (int st = 1; st < 16; st <<= 1) {       // prefix product over qubits
        const float t = __shfl_up(p, st, 16);   // segmented within 16-lane subgroup
        if (j >= st) p *= t;
    }

    if (j < NQ) out[(size_t)(row0 + ((l >> 4) & 3)) * NQ + j] = p;
}

extern "C" void kernel_launch(void* const* d_in, const int* in_sizes, int n_in,
                              void* d_out, int out_size, void* d_ws, size_t ws_size,
                              hipStream_t stream) {
    const float* x = (const float*)d_in[0];   // (8192, 512) f32
    const float* W = (const float*)d_in[1];   // (36, 512)  f32
    const float* b = (const float*)d_in[2];   // (36,)      f32
    float* out     = (float*)d_out;           // (8192, 12) f32

    const int batch = in_sizes[0] / KDIM;     // 8192
    const int grid  = batch / ROWS_PER_BLOCK; // 512
    qgate_kernel<<<grid, 256, 0, stream>>>(x, W, b, out);
}